// Round 6
// baseline (484.932 us; speedup 1.0000x reference)
//
#include <hip/hip_runtime.h>

// FlyHash-style sparse projection + per-row exact top-k threshold.
//
// Round 6: stop persisting x in registers (round 3: AGPR spill; round 5:
// scratch spill, FETCH/WRITE inflated to 90/323 MB). Only ~0.3% of x
// survives the threshold (thr ~ 4.8 > 4.0 w.h.p.), so:
//   phase 0: unconditional b128 zero-fill of the block's output region
//   phase 1: ds_read_b128 gathers (ROWS=4, best DS economics), transient
//            fold; v>=4.0 -> ballot-aggregated (f,v) candidate append + hist
//   phase 2: suffix scan -> bracket bin (bstar, above, n)
//   phase 3: exact rank-select of k-th-largest bits from the bin's members
//   phase 5: scatter candidates (>=thr ? v : 0) over the zeros
//            (WAW ordered by __syncthreads' vmcnt(0) drain)
//   phase 4: distribution-free fallback (bstar<0 / cap overflow): re-gather
//            binary search + full row rewrite. Never taken in practice.
// Registers: transient only (~40 live) -> no spill at 64-VGPR cap,
// 2 blocks/CU (LDS ~69 KB), full occupancy.
// Bit-exactness: serial f32 fold-left ascending == ref einsum accumulation;
// threshold = an actual x value's bit pattern (absmax 0 in rounds 2/4/5).

typedef float f4 __attribute__((ext_vector_type(4)));

constexpr int IN_F   = 512;
constexpr int OUT_F  = 10240;
constexpr int TPB    = 1024;
constexpr int ROWS   = 4;                 // batch rows per block
constexpr int FPT    = OUT_F / TPB;       // 10 features per thread
constexpr int NBINS  = 1024;              // per-row bins over [4,6), width 1/512
constexpr int CHUNK  = 8;
constexpr int NCHUNK = NBINS / CHUNK;     // 128 chunks per row
constexpr int NWAVES = TPB / 64;          // 16
constexpr int CAP    = 1280;              // candidates per row (mean ~825, sd ~28)
constexpr int MCAP   = 64;                // bracket-bin member cap

// ---------------------------------------------------------------------------
// Kernel 1: extract sparse indices from dense W. One wave per W row.
// Emits indices ASCENDING (required for bit-exact fold-left downstream).
// ---------------------------------------------------------------------------
__global__ __launch_bounds__(256) void extract_idx(const float* __restrict__ W,
                                                   uint4* __restrict__ packed,
                                                   int out_f) {
  int row  = blockIdx.x * 4 + (threadIdx.x >> 6);
  int lane = threadIdx.x & 63;
  if (row >= out_f) return;

  const float* wr = W + (size_t)row * IN_F;
  unsigned long long masks[8];
#pragma unroll
  for (int c = 0; c < 8; ++c) {
    float v = wr[c * 64 + lane];
    masks[c] = __ballot(v != 0.0f);   // entries are exactly 0.0 or 1.0
  }
  if (lane == 0) {
    unsigned idx[6] = {IN_F, IN_F, IN_F, IN_F, IN_F, IN_F};  // pad -> zero slot
    int n = 0;
#pragma unroll
    for (int c = 0; c < 8; ++c) {
      unsigned long long m = masks[c];
      while (m && n < 6) {
        int b = __builtin_ctzll(m);
        idx[n++] = (unsigned)(c * 64 + b);
        m &= m - 1;
      }
    }
    uint4 r;
    r.x = idx[0] | (idx[1] << 16);
    r.y = idx[2] | (idx[3] << 16);
    r.z = idx[4] | (idx[5] << 16);
    r.w = (unsigned)n;
    packed[row] = r;
  }
}

// Serial fold of one row-component r (bit-identical to phase-1's fold).
__device__ __forceinline__ float row_val(const f4* in4, uint4 p, int r) {
  const float* b = (const float*)in4;
  float s = b[(p.x & 0xFFFFu) * 4 + r];
  s += b[(p.x >> 16) * 4 + r];
  s += b[(p.y & 0xFFFFu) * 4 + r];
  s += b[(p.y >> 16) * 4 + r];
  s += b[(p.z & 0xFFFFu) * 4 + r];
  s += b[(p.z >> 16) * 4 + r];
  return s;
}

// ---------------------------------------------------------------------------
// Kernel 2: 4 batch rows per block, 1024 threads, transient x.
// ---------------------------------------------------------------------------
__global__ __launch_bounds__(TPB, 8) void fly_hash(const float* __restrict__ inp,
                                                   const uint4* __restrict__ packed,
                                                   const int* __restrict__ kptr,
                                                   float* __restrict__ out) {
  __shared__ f4    in4[IN_F + 1];        // 8.2 KB; [IN_F] = zero slot for pads
  __shared__ int   hist[ROWS * NBINS];   // 16 KB
  __shared__ int   csum[ROWS * NCHUNK];  // 2 KB
  __shared__ int   wsum[NWAVES];
  __shared__ uint2 cand[ROWS][CAP];      // 40 KB: (feature, bits(v))
  __shared__ float mem[ROWS][MCAP];      // bracket-bin members
  __shared__ int   sh_bstar[ROWS], sh_above[ROWS], sh_n[ROWS], sh_cnt[ROWS];
  __shared__ float sh_thr[ROWS];
  __shared__ int   sh_need[ROWS];

  const int tid  = threadIdx.x;
  const int lane = tid & 63;
  const int wid  = tid >> 6;
  const int row0 = blockIdx.x * ROWS;
  const int k    = *kptr;                // hash_length (32)
  float* const obase = out + (size_t)row0 * OUT_F;

  // --- phase 0: stage input (transposed), zero hist, zero-fill output ----
  if (tid < IN_F) {
    const float* p = inp + (size_t)row0 * IN_F + tid;
    f4 v;
    v.x = p[0];
    v.y = p[IN_F];
    v.z = p[2 * IN_F];
    v.w = p[3 * IN_F];
    in4[tid] = v;
  } else if (tid == IN_F) {
    f4 z = {0.0f, 0.0f, 0.0f, 0.0f};
    in4[IN_F] = z;
  }
  if (tid < ROWS) { sh_bstar[tid] = -1; sh_cnt[tid] = 0; }
  for (int i = tid; i < ROWS * NBINS; i += TPB) hist[i] = 0;
  {
    f4 z = {0.0f, 0.0f, 0.0f, 0.0f};
    f4* oz = (f4*)obase;                 // 4 rows contiguous = 10240 f4s
#pragma unroll
    for (int j = 0; j < FPT; ++j) oz[tid + j * TPB] = z;  // full-line b128 zeros
  }
  __syncthreads();

  // --- phase 1: transient gather-fold; candidates + histogram ------------
#pragma unroll 2
  for (int i = 0; i < FPT; ++i) {
    const int f = tid + i * TPB;
    uint4 r = packed[f];
    f4 s = in4[r.x & 0xFFFFu];           // ds_read_b128: 4 rows per gather
    s += in4[r.x >> 16];
    s += in4[r.y & 0xFFFFu];
    s += in4[r.y >> 16];
    s += in4[r.z & 0xFFFFu];
    s += in4[r.z >> 16];
#pragma unroll
    for (int rr = 0; rr < ROWS; ++rr) {
      float v = s[rr];
      unsigned long long m = __ballot(v >= 4.0f);
      if (m) {
        int lead = __ffsll(m) - 1;
        int base = 0;
        if (lane == lead) base = atomicAdd(&sh_cnt[rr], (int)__popcll(m));
        base = __shfl(base, lead);
        if (v >= 4.0f) {
          int slot = base + (int)__popcll(m & ((1ull << lane) - 1ull));
          if (slot < CAP) cand[rr][slot] = make_uint2((unsigned)f, __float_as_uint(v));
          int b = (int)((v - 4.0f) * 512.0f);   // EXACT key (Sterbenz + pow2)
          b = b > NBINS - 1 ? NBINS - 1 : b;
          atomicAdd(&hist[rr * NBINS + b], 1);
        }
      }
    }
  }
  __syncthreads();

  // --- phase 2: per-row bracket bin via suffix scan ----------------------
  {
    const bool active = tid < ROWS * NCHUNK;   // 512 of 1024
    const int r = tid >> 7;
    const int c = tid & (NCHUNK - 1);
    if (active) {
      const int base = r * NBINS + c * CHUNK;
      int ssum = 0;
#pragma unroll
      for (int j = 0; j < CHUNK; ++j) ssum += hist[base + j];
      csum[tid] = ssum;
    }
    __syncthreads();
    for (int st = 1; st < NCHUNK; st <<= 1) {
      int v = 0;
      if (active) v = csum[tid] + ((c + st < NCHUNK) ? csum[tid + st] : 0);
      __syncthreads();
      if (active) csum[tid] = v;
      __syncthreads();
    }
    if (active) {
      int above_chunk = (c + 1 < NCHUNK) ? csum[tid + 1] : 0;
      if (csum[tid] >= k && above_chunk < k) {   // unique crossing chunk
        int acc = above_chunk;
        int bsel = c * CHUNK, abv = above_chunk;
        for (int b = c * CHUNK + CHUNK - 1; b >= c * CHUNK; --b) {
          int h = hist[r * NBINS + b];
          if (acc + h >= k) { bsel = b; abv = acc; break; }
          acc += h;
        }
        sh_bstar[r] = bsel;
        sh_above[r] = abv;
        sh_n[r]     = hist[r * NBINS + bsel];
      }
    }
  }
  __syncthreads();

  // --- phase 3: wave r collects bracket members, rank-selects threshold --
  if (wid < ROWS) {
    const int r   = wid;
    const int bst = sh_bstar[r];
    const int cnt = sh_cnt[r];
    bool ok = (bst >= 0) && (cnt <= CAP);
    const int n = ok ? sh_n[r] : 0;
    ok = ok && (n >= 1) && (n <= MCAP);
    if (ok) {
      int nm = 0;
      for (int base = 0; base < cnt; base += 64) {
        int idx = base + lane;
        bool act = idx < cnt;
        uint2 e = act ? cand[r][idx] : make_uint2(0u, 0u);
        float v = __uint_as_float(e.y);
        int b = (int)((v - 4.0f) * 512.0f);
        b = b > NBINS - 1 ? NBINS - 1 : b;
        bool ism = act && (b == bst);
        unsigned long long m = __ballot(ism);
        if (ism) {
          int ofs = nm + (int)__popcll(m & ((1ull << lane) - 1ull));
          if (ofs < MCAP) mem[r][ofs] = v;
        }
        nm += (int)__popcll(m);
      }
      const int j = k - sh_above[r];           // 1 <= j <= n
      float vl = (lane < n) ? mem[r][lane] : -1.0f;
      int cgt = 0, cge = 0;
      for (int mi = 0; mi < n; ++mi) {
        float u = mem[r][mi];                  // broadcast LDS read
        cgt += (u > vl);
        cge += (u >= vl);
      }
      if (lane < n && cgt < j && cge >= j) sh_thr[r] = vl;  // exact k-th bits
      if (lane == 0) sh_need[r] = 0;
    } else {
      if (lane == 0) sh_need[r] = 1;
    }
  }
  __syncthreads();

  // --- phase 4: fallback (block-uniform; never taken in practice) --------
#pragma unroll 1
  for (int r = 0; r < ROWS; ++r) {
    if (!sh_need[r]) continue;
    unsigned lo = 0u, hi = __float_as_uint(8.0f);
    while (lo < hi) {
      unsigned mid = lo + ((hi - lo + 1u) >> 1);
      float fm = __uint_as_float(mid);
      int c = 0;
      for (int i = 0; i < FPT; ++i) {
        uint4 p = packed[tid + i * TPB];
        c += (int)__popcll(__ballot(row_val(in4, p, r) >= fm));
      }
      if (lane == 0) wsum[wid] = c;
      __syncthreads();
      int tot = 0;
#pragma unroll
      for (int w = 0; w < NWAVES; ++w) tot += wsum[w];
      if (tot >= k) lo = mid; else hi = mid - 1u;
      __syncthreads();
    }
    float thr = __uint_as_float(lo);
    for (int i = 0; i < FPT; ++i) {
      int f = tid + i * TPB;
      float v = row_val(in4, packed[f], r);
      obase[(size_t)r * OUT_F + f] = (v >= thr) ? v : 0.0f;
    }
  }

  // --- phase 5: scatter candidates over the zeros ------------------------
#pragma unroll
  for (int r = 0; r < ROWS; ++r) {
    if (sh_need[r]) continue;
    const int cn = sh_cnt[r];                  // <= CAP here
    const float tr = sh_thr[r];
    float* orow = obase + (size_t)r * OUT_F;
    for (int idx = tid; idx < cn; idx += TPB) {
      uint2 e = cand[r][idx];
      float v = __uint_as_float(e.y);
      orow[e.x] = (v >= tr) ? v : 0.0f;
    }
  }
}

// ---------------------------------------------------------------------------
extern "C" void kernel_launch(void* const* d_in, const int* in_sizes, int n_in,
                              void* d_out, int out_size, void* d_ws, size_t ws_size,
                              hipStream_t stream) {
  const float* inp = (const float*)d_in[0];
  const float* W   = (const float*)d_in[1];
  const int* kptr  = (const int*)d_in[2];
  float* out       = (float*)d_out;

  const int batch = in_sizes[0] / IN_F;   // 4096
  const int out_f = in_sizes[1] / IN_F;   // 10240

  uint4* packed = (uint4*)d_ws;           // 10240 * 16 B = 160 KB scratch

  hipLaunchKernelGGL(extract_idx, dim3((out_f + 3) / 4), dim3(256), 0, stream,
                     W, packed, out_f);
  hipLaunchKernelGGL(fly_hash, dim3(batch / ROWS), dim3(TPB), 0, stream,
                     inp, packed, kptr, out);
}

// Round 7
// 277.810 us; speedup vs baseline: 1.7456x; 1.7456x over previous
//
#include <hip/hip_runtime.h>

// FlyHash-style sparse projection + per-row exact top-k threshold.
//
// Round 7 = R3's gather economics + R4's thresholding.
//  - ROWS=4, TPB=512, ds_read_b128 gathers: 0.98M wave DS-ops for the
//    1.0 GB LDS gather traffic (best B/cyc; R4's b64 needed 1.97M).
//  - __launch_bounds__(512,4): 128-reg budget. x4[20]=80 regs lands in
//    64V+64A (R3 proved: FETCH/WRITE stayed clean, no scratch). AGPR
//    round-trips are cheap because x4 is read exactly TWICE after
//    phase 1 (bin-collect + write) — R3's killer was its 13-iter ballot
//    search re-reading all 80 AGPRs per iteration; R4's list-select
//    eliminated that (zero search iterations in the common path).
//  - Nontemporal output stores (168 MB streaming).
// Bit-exactness (absmax 0 in R2/R4/R5/R6): per-component serial f32
// fold-left in ascending index order == ref einsum accumulation;
// threshold = an actual x value's bit pattern.

typedef float f4 __attribute__((ext_vector_type(4)));

constexpr int IN_F   = 512;
constexpr int OUT_F  = 10240;
constexpr int TPB    = 512;
constexpr int ROWS   = 4;                 // batch rows per block
constexpr int FPT    = OUT_F / TPB;       // 20 features per thread
constexpr int NBINS  = 1024;              // per-row bins over [4,6), width 1/512
constexpr int CHUNK  = 8;
constexpr int NCHUNK = NBINS / CHUNK;     // 128 chunks per row
constexpr int NWAVES = TPB / 64;          // 8
constexpr int CAP    = 64;                // bracket-bin list capacity per row

static_assert(ROWS * NCHUNK == TPB, "scan assumes one chunk per thread");

// ---------------------------------------------------------------------------
// Kernel 1: extract sparse indices from dense W. One wave per W row.
// Emits indices ASCENDING (required for bit-exact fold-left downstream).
// ---------------------------------------------------------------------------
__global__ __launch_bounds__(256) void extract_idx(const float* __restrict__ W,
                                                   uint4* __restrict__ packed,
                                                   int out_f) {
  int row  = blockIdx.x * 4 + (threadIdx.x >> 6);
  int lane = threadIdx.x & 63;
  if (row >= out_f) return;

  const float* wr = W + (size_t)row * IN_F;
  unsigned long long masks[8];
#pragma unroll
  for (int c = 0; c < 8; ++c) {
    float v = wr[c * 64 + lane];
    masks[c] = __ballot(v != 0.0f);   // entries are exactly 0.0 or 1.0
  }
  if (lane == 0) {
    unsigned idx[6] = {IN_F, IN_F, IN_F, IN_F, IN_F, IN_F};  // pad -> zero slot
    int n = 0;
#pragma unroll
    for (int c = 0; c < 8; ++c) {
      unsigned long long m = masks[c];
      while (m && n < 6) {
        int b = __builtin_ctzll(m);
        idx[n++] = (unsigned)(c * 64 + b);
        m &= m - 1;
      }
    }
    uint4 r;
    r.x = idx[0] | (idx[1] << 16);
    r.y = idx[2] | (idx[3] << 16);
    r.z = idx[4] | (idx[5] << 16);
    r.w = (unsigned)n;
    packed[row] = r;
  }
}

// ---------------------------------------------------------------------------
// Kernel 2: 4 batch rows per block, 512 threads, persisted x4 + list-select.
// ---------------------------------------------------------------------------
__global__ __launch_bounds__(TPB, 4) void fly_hash(const float* __restrict__ inp,
                                                   const uint4* __restrict__ packed,
                                                   const int* __restrict__ kptr,
                                                   float* __restrict__ out) {
  __shared__ f4    in4[IN_F + 1];       // 8.2 KB; [IN_F] = zero slot for pads
  __shared__ int   hist[ROWS * NBINS];  // 16 KB
  __shared__ int   csum[ROWS * NCHUNK]; // 2 KB
  __shared__ int   wsum[NWAVES][ROWS];
  __shared__ int   sh_bstar[ROWS], sh_above[ROWS], sh_n[ROWS], sh_cnt[ROWS];
  __shared__ float sh_list[ROWS][CAP];
  __shared__ float sh_thr[ROWS];
  __shared__ int   sh_need[ROWS];       // 1 -> fallback binary search

  const int tid  = threadIdx.x;
  const int row0 = blockIdx.x * ROWS;
  const int k    = *kptr;               // hash_length (32)

  // --- stage 4 input rows transposed into LDS ---------------------------
  {
    const float* p = inp + (size_t)row0 * IN_F + tid;
    f4 v;
    v.x = p[0];
    v.y = p[IN_F];
    v.z = p[2 * IN_F];
    v.w = p[3 * IN_F];
    in4[tid] = v;                       // ds_write_b128, conflict-free
  }
  if (tid == 0) { f4 z = {0.0f, 0.0f, 0.0f, 0.0f}; in4[IN_F] = z; }
  if (tid < ROWS) { sh_bstar[tid] = -1; sh_cnt[tid] = 0; }
  for (int i = tid; i < ROWS * NBINS; i += TPB) hist[i] = 0;
  __syncthreads();

  // --- phase 1: compute x (bit-exact serial fold-left) + histogram -------
  f4 x4[FPT];
#pragma unroll 2
  for (int i = 0; i < FPT; ++i) {
    uint4 r = packed[tid + i * TPB];
    f4 s = in4[r.x & 0xFFFFu];          // ds_read_b128: 4 rows per gather
    s += in4[r.x >> 16];
    s += in4[r.y & 0xFFFFu];
    s += in4[r.y >> 16];
    s += in4[r.z & 0xFFFFu];
    s += in4[r.z >> 16];
    x4[i] = s;
#pragma unroll
    for (int rr = 0; rr < ROWS; ++rr) {
      float v = s[rr];
      if (v >= 4.0f) {                  // top-32 of 10240 ~ 4.8; bin >=4 only
        int b = (int)((v - 4.0f) * 512.0f);    // EXACT key (Sterbenz + pow2)
        b = b > NBINS - 1 ? NBINS - 1 : b;
        atomicAdd(&hist[rr * NBINS + b], 1);
      }
    }
  }
  __syncthreads();

  // --- phase 2: per-row bracket bin via suffix scan (all 512 active) -----
  {
    const int r = tid >> 7;             // row (0..3)
    const int c = tid & (NCHUNK - 1);   // chunk within row
    const int base = r * NBINS + c * CHUNK;
    int ssum = 0;
#pragma unroll
    for (int j = 0; j < CHUNK; ++j) ssum += hist[base + j];
    csum[tid] = ssum;
    __syncthreads();
    for (int st = 1; st < NCHUNK; st <<= 1) {
      int v = csum[tid] + ((c + st < NCHUNK) ? csum[tid + st] : 0);
      __syncthreads();
      csum[tid] = v;
      __syncthreads();
    }
    int above_chunk = (c + 1 < NCHUNK) ? csum[tid + 1] : 0;
    if (csum[tid] >= k && above_chunk < k) {   // unique crossing chunk
      int acc = above_chunk;
      int bsel = c * CHUNK, abv = above_chunk;
      for (int b = c * CHUNK + CHUNK - 1; b >= c * CHUNK; --b) {
        int h = hist[r * NBINS + b];
        if (acc + h >= k) { bsel = b; abv = acc; break; }
        acc += h;
      }
      sh_bstar[r] = bsel;
      sh_above[r] = abv;
      sh_n[r]     = hist[r * NBINS + bsel];
    }
  }
  __syncthreads();

  // --- phase 3a: collect bracket-bin members into per-row lists ----------
  {
    const int b0 = sh_bstar[0], b1 = sh_bstar[1];
    const int b2 = sh_bstar[2], b3 = sh_bstar[3];
#pragma unroll
    for (int i = 0; i < FPT; ++i) {
      f4 s = x4[i];
#pragma unroll
      for (int rr = 0; rr < ROWS; ++rr) {
        float v = s[rr];
        int bb = (rr == 0) ? b0 : (rr == 1) ? b1 : (rr == 2) ? b2 : b3;
        if (v >= 4.0f) {
          int b = (int)((v - 4.0f) * 512.0f);
          b = b > NBINS - 1 ? NBINS - 1 : b;
          if (b == bb) {
            int p = atomicAdd(&sh_cnt[rr], 1);
            if (p < CAP) sh_list[rr][p] = v;
          }
        }
      }
    }
  }
  __syncthreads();

  // --- phase 3b: wave r rank-selects the (k-above)-th largest in its list -
  {
    const int wid  = tid >> 6;
    const int lane = tid & 63;
    if (wid < ROWS) {
      const int r   = wid;
      const int bst = sh_bstar[r];
      const int n   = (bst >= 0) ? sh_n[r] : CAP + 1;
      if (bst >= 0 && n <= CAP) {
        const int j = k - sh_above[r];          // 1 <= j <= n
        float vl = (lane < n) ? sh_list[r][lane] : -1.0f;
        int cgt = 0, cge = 0;
        for (int m = 0; m < n; ++m) {
          float u = sh_list[r][m];              // broadcast LDS read
          cgt += (u > vl);
          cge += (u >= vl);
        }
        if (lane < n && cgt < j && cge >= j) sh_thr[r] = vl;  // exact bits
        if (lane == 0) sh_need[r] = 0;
      } else {
        if (lane == 0) sh_need[r] = 1;          // overflow / no bracket
      }
    }
  }
  __syncthreads();

  // --- phase 4: fallback bit-search (distribution-free; normally skipped) -
  unsigned lo[ROWS], hi[ROWS];
#pragma unroll
  for (int r = 0; r < ROWS; ++r) {
    if (sh_need[r]) {
      int b = sh_bstar[r];
      if (b < 0) {
        lo[r] = 0u;
        hi[r] = __float_as_uint(4.0f + (1.0f / 512.0f));
      } else {
        lo[r] = __float_as_uint(4.0f + (float)b * (1.0f / 512.0f));
        hi[r] = __float_as_uint(4.0f + (float)(b + 1) * (1.0f / 512.0f));
      }
    } else {
      lo[r] = hi[r] = 0u;
    }
  }
  {
    const int lane = tid & 63;
    const int wid  = tid >> 6;
    while (lo[0] < hi[0] || lo[1] < hi[1] || lo[2] < hi[2] || lo[3] < hi[3]) {
      unsigned mid[ROWS];
      float fm[ROWS];
#pragma unroll
      for (int r = 0; r < ROWS; ++r) {
        mid[r] = lo[r] + ((hi[r] - lo[r] + 1u) >> 1);
        fm[r] = __uint_as_float(mid[r]);
      }
      int c0 = 0, c1 = 0, c2 = 0, c3 = 0;
#pragma unroll
      for (int i = 0; i < FPT; ++i) {
        c0 += (int)__popcll(__ballot(x4[i].x >= fm[0]));
        c1 += (int)__popcll(__ballot(x4[i].y >= fm[1]));
        c2 += (int)__popcll(__ballot(x4[i].z >= fm[2]));
        c3 += (int)__popcll(__ballot(x4[i].w >= fm[3]));
      }
      if (lane == 0) {
        wsum[wid][0] = c0; wsum[wid][1] = c1;
        wsum[wid][2] = c2; wsum[wid][3] = c3;
      }
      __syncthreads();
      int tot[ROWS] = {0, 0, 0, 0};
#pragma unroll
      for (int w = 0; w < NWAVES; ++w)
#pragma unroll
        for (int r = 0; r < ROWS; ++r) tot[r] += wsum[w][r];
#pragma unroll
      for (int r = 0; r < ROWS; ++r) {
        if (lo[r] < hi[r]) {
          if (tot[r] >= k) lo[r] = mid[r]; else hi[r] = mid[r] - 1u;
        }
      }
      __syncthreads();
    }
  }
  const float t0 = sh_need[0] ? __uint_as_float(lo[0]) : sh_thr[0];
  const float t1 = sh_need[1] ? __uint_as_float(lo[1]) : sh_thr[1];
  const float t2 = sh_need[2] ? __uint_as_float(lo[2]) : sh_thr[2];
  const float t3 = sh_need[3] ? __uint_as_float(lo[3]) : sh_thr[3];

  // --- phase 5: thresholded writes, 4 coalesced nontemporal streams ------
  float* o0 = out + (size_t)(row0 + 0) * OUT_F;
  float* o1 = out + (size_t)(row0 + 1) * OUT_F;
  float* o2 = out + (size_t)(row0 + 2) * OUT_F;
  float* o3 = out + (size_t)(row0 + 3) * OUT_F;
#pragma unroll
  for (int i = 0; i < FPT; ++i) {
    int f = tid + i * TPB;
    f4 v = x4[i];
    __builtin_nontemporal_store((v.x >= t0) ? v.x : 0.0f, &o0[f]);
    __builtin_nontemporal_store((v.y >= t1) ? v.y : 0.0f, &o1[f]);
    __builtin_nontemporal_store((v.z >= t2) ? v.z : 0.0f, &o2[f]);
    __builtin_nontemporal_store((v.w >= t3) ? v.w : 0.0f, &o3[f]);
  }
}

// ---------------------------------------------------------------------------
extern "C" void kernel_launch(void* const* d_in, const int* in_sizes, int n_in,
                              void* d_out, int out_size, void* d_ws, size_t ws_size,
                              hipStream_t stream) {
  const float* inp = (const float*)d_in[0];
  const float* W   = (const float*)d_in[1];
  const int* kptr  = (const int*)d_in[2];
  float* out       = (float*)d_out;

  const int batch = in_sizes[0] / IN_F;   // 4096
  const int out_f = in_sizes[1] / IN_F;   // 10240

  uint4* packed = (uint4*)d_ws;           // 10240 * 16 B = 160 KB scratch

  hipLaunchKernelGGL(extract_idx, dim3((out_f + 3) / 4), dim3(256), 0, stream,
                     W, packed, out_f);
  hipLaunchKernelGGL(fly_hash, dim3(batch / ROWS), dim3(TPB), 0, stream,
                     inp, packed, kptr, out);
}

// Round 8
// 239.894 us; speedup vs baseline: 2.0214x; 1.1581x over previous
//
#include <hip/hip_runtime.h>

// FlyHash-style sparse projection + per-row exact top-k threshold.
//
// Round 8. R7 (108us, best) was HBM-bound on SCRATCH SPILL traffic
// (FETCH 169 MB / WRITE 327 MB vs ideal 7/166): x4[20]=80 persisted floats
// at TPB=512 is not reliably allocatable (R3: AGPR; R7: scratch). Fix:
// make spilling impossible. TPB=1024, ROWS=4, FPT=10 -> x4[10]=40 persisted
// VGPRs; __launch_bounds__(1024,4) -> 128-VGPR budget (1 block/CU,
// 16 waves/CU). 40+~30 transient << 128. Same ds_read_b128 gather economics
// as R7 (0.98M wave-ops for 1.0 GB LDS traffic), same zero-iteration
// list-select; the (normally dead) fallback now RECOMPUTES x from LDS
// instead of referencing x4, removing register pressure across it.
// Bit-exactness (absmax 0 in R2/R4-R7): per-component serial f32 fold-left
// ascending == ref einsum accumulation; threshold = an actual x value's bits.

typedef float f4 __attribute__((ext_vector_type(4)));

constexpr int IN_F   = 512;
constexpr int OUT_F  = 10240;
constexpr int TPB    = 1024;
constexpr int ROWS   = 4;                 // batch rows per block
constexpr int FPT    = OUT_F / TPB;       // 10 features per thread
constexpr int NBINS  = 1024;              // per-row bins over [4,6), width 1/512
constexpr int CHUNK  = 8;
constexpr int NCHUNK = NBINS / CHUNK;     // 128 chunks per row
constexpr int NWAVES = TPB / 64;          // 16
constexpr int CAP    = 64;                // bracket-bin list capacity per row

// ---------------------------------------------------------------------------
// Kernel 1: extract sparse indices from dense W. One wave per W row.
// Emits indices ASCENDING (required for bit-exact fold-left downstream).
// ---------------------------------------------------------------------------
__global__ __launch_bounds__(256) void extract_idx(const float* __restrict__ W,
                                                   uint4* __restrict__ packed,
                                                   int out_f) {
  int row  = blockIdx.x * 4 + (threadIdx.x >> 6);
  int lane = threadIdx.x & 63;
  if (row >= out_f) return;

  const float* wr = W + (size_t)row * IN_F;
  unsigned long long masks[8];
#pragma unroll
  for (int c = 0; c < 8; ++c) {
    float v = wr[c * 64 + lane];
    masks[c] = __ballot(v != 0.0f);   // entries are exactly 0.0 or 1.0
  }
  if (lane == 0) {
    unsigned idx[6] = {IN_F, IN_F, IN_F, IN_F, IN_F, IN_F};  // pad -> zero slot
    int n = 0;
#pragma unroll
    for (int c = 0; c < 8; ++c) {
      unsigned long long m = masks[c];
      while (m && n < 6) {
        int b = __builtin_ctzll(m);
        idx[n++] = (unsigned)(c * 64 + b);
        m &= m - 1;
      }
    }
    uint4 r;
    r.x = idx[0] | (idx[1] << 16);
    r.y = idx[2] | (idx[3] << 16);
    r.z = idx[4] | (idx[5] << 16);
    r.w = (unsigned)n;
    packed[row] = r;
  }
}

// Serial fold of one row-component r (bit-identical to phase-1's fold).
__device__ __forceinline__ float row_val(const f4* in4, uint4 p, int r) {
  const float* b = (const float*)in4;
  float s = b[(p.x & 0xFFFFu) * 4 + r];
  s += b[(p.x >> 16) * 4 + r];
  s += b[(p.y & 0xFFFFu) * 4 + r];
  s += b[(p.y >> 16) * 4 + r];
  s += b[(p.z & 0xFFFFu) * 4 + r];
  s += b[(p.z >> 16) * 4 + r];
  return s;
}

// ---------------------------------------------------------------------------
// Kernel 2: 4 batch rows per block, 1024 threads, x4[10] persisted (40 VGPR).
// ---------------------------------------------------------------------------
__global__ __launch_bounds__(TPB, 4) void fly_hash(const float* __restrict__ inp,
                                                   const uint4* __restrict__ packed,
                                                   const int* __restrict__ kptr,
                                                   float* __restrict__ out) {
  __shared__ f4    in4[IN_F + 1];       // 8.2 KB; [IN_F] = zero slot for pads
  __shared__ int   hist[ROWS * NBINS];  // 16 KB
  __shared__ int   csum[ROWS * NCHUNK]; // 2 KB
  __shared__ int   wsum[NWAVES];
  __shared__ int   sh_bstar[ROWS], sh_above[ROWS], sh_n[ROWS], sh_cnt[ROWS];
  __shared__ float sh_list[ROWS][CAP];
  __shared__ float sh_thr[ROWS];
  __shared__ int   sh_need[ROWS];       // 1 -> fallback binary search

  const int tid  = threadIdx.x;
  const int lane = tid & 63;
  const int wid  = tid >> 6;
  const int row0 = blockIdx.x * ROWS;
  const int k    = *kptr;               // hash_length (32)

  // --- stage 4 input rows transposed into LDS ---------------------------
  if (tid < IN_F) {
    const float* p = inp + (size_t)row0 * IN_F + tid;
    f4 v;
    v.x = p[0];
    v.y = p[IN_F];
    v.z = p[2 * IN_F];
    v.w = p[3 * IN_F];
    in4[tid] = v;                       // ds_write_b128, conflict-free
  } else if (tid == IN_F) {
    f4 z = {0.0f, 0.0f, 0.0f, 0.0f};
    in4[IN_F] = z;
  }
  if (tid < ROWS) { sh_bstar[tid] = -1; sh_cnt[tid] = 0; }
  for (int i = tid; i < ROWS * NBINS; i += TPB) hist[i] = 0;
  __syncthreads();

  // --- phase 1: compute x (bit-exact serial fold-left) + histogram -------
  f4 x4[FPT];
#pragma unroll
  for (int i = 0; i < FPT; ++i) {
    uint4 r = packed[tid + i * TPB];
    f4 s = in4[r.x & 0xFFFFu];          // ds_read_b128: 4 rows per gather
    s += in4[r.x >> 16];
    s += in4[r.y & 0xFFFFu];
    s += in4[r.y >> 16];
    s += in4[r.z & 0xFFFFu];
    s += in4[r.z >> 16];
    x4[i] = s;
#pragma unroll
    for (int rr = 0; rr < ROWS; ++rr) {
      float v = s[rr];
      if (v >= 4.0f) {                  // top-32 of 10240 ~ 4.8; bin >=4 only
        int b = (int)((v - 4.0f) * 512.0f);    // EXACT key (Sterbenz + pow2)
        b = b > NBINS - 1 ? NBINS - 1 : b;
        atomicAdd(&hist[rr * NBINS + b], 1);
      }
    }
  }
  __syncthreads();

  // --- phase 2: per-row bracket bin via suffix scan (512 of 1024 active) --
  {
    const bool active = tid < ROWS * NCHUNK;   // 512
    const int r = tid >> 7;             // row (0..3) when active
    const int c = tid & (NCHUNK - 1);   // chunk within row
    if (active) {
      const int base = r * NBINS + c * CHUNK;
      int ssum = 0;
#pragma unroll
      for (int j = 0; j < CHUNK; ++j) ssum += hist[base + j];
      csum[tid] = ssum;
    }
    __syncthreads();
    for (int st = 1; st < NCHUNK; st <<= 1) {
      int v = 0;
      if (active) v = csum[tid] + ((c + st < NCHUNK) ? csum[tid + st] : 0);
      __syncthreads();
      if (active) csum[tid] = v;
      __syncthreads();
    }
    if (active) {
      int above_chunk = (c + 1 < NCHUNK) ? csum[tid + 1] : 0;
      if (csum[tid] >= k && above_chunk < k) {   // unique crossing chunk
        int acc = above_chunk;
        int bsel = c * CHUNK, abv = above_chunk;
        for (int b = c * CHUNK + CHUNK - 1; b >= c * CHUNK; --b) {
          int h = hist[r * NBINS + b];
          if (acc + h >= k) { bsel = b; abv = acc; break; }
          acc += h;
        }
        sh_bstar[r] = bsel;
        sh_above[r] = abv;
        sh_n[r]     = hist[r * NBINS + bsel];
      }
    }
  }
  __syncthreads();

  // --- phase 3a: collect bracket-bin members into per-row lists ----------
  {
    const int b0 = sh_bstar[0], b1 = sh_bstar[1];
    const int b2 = sh_bstar[2], b3 = sh_bstar[3];
#pragma unroll
    for (int i = 0; i < FPT; ++i) {
      f4 s = x4[i];
#pragma unroll
      for (int rr = 0; rr < ROWS; ++rr) {
        float v = s[rr];
        int bb = (rr == 0) ? b0 : (rr == 1) ? b1 : (rr == 2) ? b2 : b3;
        if (v >= 4.0f) {
          int b = (int)((v - 4.0f) * 512.0f);
          b = b > NBINS - 1 ? NBINS - 1 : b;
          if (b == bb) {
            int p = atomicAdd(&sh_cnt[rr], 1);
            if (p < CAP) sh_list[rr][p] = v;
          }
        }
      }
    }
  }
  __syncthreads();

  // --- phase 3b: wave r rank-selects the (k-above)-th largest in its list -
  if (wid < ROWS) {
    const int r   = wid;
    const int bst = sh_bstar[r];
    const int n   = (bst >= 0) ? sh_n[r] : CAP + 1;
    if (bst >= 0 && n <= CAP && sh_cnt[r] <= CAP) {
      const int j = k - sh_above[r];            // 1 <= j <= n
      float vl = (lane < n) ? sh_list[r][lane] : -1.0f;
      int cgt = 0, cge = 0;
      for (int m = 0; m < n; ++m) {
        float u = sh_list[r][m];                // broadcast LDS read
        cgt += (u > vl);
        cge += (u >= vl);
      }
      if (lane < n && cgt < j && cge >= j) sh_thr[r] = vl;  // exact k-th bits
      if (lane == 0) sh_need[r] = 0;
    } else {
      if (lane == 0) sh_need[r] = 1;            // overflow / no bracket
    }
  }
  __syncthreads();

  // --- phase 4: fallback (recomputes from LDS; normally never taken) -----
#pragma unroll 1
  for (int r = 0; r < ROWS; ++r) {
    if (!sh_need[r]) continue;
    unsigned lo = 0u, hi = __float_as_uint(8.0f);
    while (lo < hi) {
      unsigned mid = lo + ((hi - lo + 1u) >> 1);
      float fm = __uint_as_float(mid);
      int c = 0;
      for (int i = 0; i < FPT; ++i) {
        uint4 p = packed[tid + i * TPB];
        c += (int)__popcll(__ballot(row_val(in4, p, r) >= fm));
      }
      if (lane == 0) wsum[wid] = c;
      __syncthreads();
      int tot = 0;
#pragma unroll
      for (int w = 0; w < NWAVES; ++w) tot += wsum[w];
      if (tot >= k) lo = mid; else hi = mid - 1u;
      __syncthreads();
    }
    if (tid == 0) sh_thr[r] = __uint_as_float(lo);
    __syncthreads();
  }
  const float t0 = sh_thr[0];
  const float t1 = sh_thr[1];
  const float t2 = sh_thr[2];
  const float t3 = sh_thr[3];

  // --- phase 5: thresholded writes, 4 coalesced nontemporal streams ------
  float* o0 = out + (size_t)(row0 + 0) * OUT_F;
  float* o1 = out + (size_t)(row0 + 1) * OUT_F;
  float* o2 = out + (size_t)(row0 + 2) * OUT_F;
  float* o3 = out + (size_t)(row0 + 3) * OUT_F;
#pragma unroll
  for (int i = 0; i < FPT; ++i) {
    int f = tid + i * TPB;
    f4 v = x4[i];
    __builtin_nontemporal_store((v.x >= t0) ? v.x : 0.0f, &o0[f]);
    __builtin_nontemporal_store((v.y >= t1) ? v.y : 0.0f, &o1[f]);
    __builtin_nontemporal_store((v.z >= t2) ? v.z : 0.0f, &o2[f]);
    __builtin_nontemporal_store((v.w >= t3) ? v.w : 0.0f, &o3[f]);
  }
}

// ---------------------------------------------------------------------------
extern "C" void kernel_launch(void* const* d_in, const int* in_sizes, int n_in,
                              void* d_out, int out_size, void* d_ws, size_t ws_size,
                              hipStream_t stream) {
  const float* inp = (const float*)d_in[0];
  const float* W   = (const float*)d_in[1];
  const int* kptr  = (const int*)d_in[2];
  float* out       = (float*)d_out;

  const int batch = in_sizes[0] / IN_F;   // 4096
  const int out_f = in_sizes[1] / IN_F;   // 10240

  uint4* packed = (uint4*)d_ws;           // 10240 * 16 B = 160 KB scratch

  hipLaunchKernelGGL(extract_idx, dim3((out_f + 3) / 4), dim3(256), 0, stream,
                     W, packed, out_f);
  hipLaunchKernelGGL(fly_hash, dim3(batch / ROWS), dim3(TPB), 0, stream,
                     inp, packed, kptr, out);
}